// Round 6
// baseline (444.222 us; speedup 1.0000x reference)
//
#include <hip/hip_runtime.h>
#include <stdint.h>

// ---------------------------------------------------------------------------
// LocalAtomAttention v4 on gfx950 — MFMA attention + clean HBM streams.
//   x:[16,4096,4,128] f32, mask:[16,4096,4] int, Wq/bq/Wk/bk/Wv/bv/Wo/bo.
// v3 post-mortem: scattered 64B partial-line out stores at 4 blocks/CU caused
// write-allocate + partial-line eviction: WRITE 131->605 MB, FETCH 67->286 MB.
// v4 = v3 with the store side fixed:
//   - final f32 tile staged in LDS (3rd alias of smem), then block-wide
//     coalesced float4 stores: one contiguous 32KB stream, full lines only
//   - nontemporal stores (out is write-once) keep L2/L3 free for x
//   - x staging, MFMA projection/attention/out-proj core identical to v3
// ---------------------------------------------------------------------------

typedef __fp16 f16;   // storage-only; builtins want __fp16 ext-vectors
typedef f16   f16x2 __attribute__((ext_vector_type(2)));
typedef f16   f16x4 __attribute__((ext_vector_type(4)));
typedef f16   f16x8 __attribute__((ext_vector_type(8)));
typedef float f32x4 __attribute__((ext_vector_type(4)));

#define N_RES 65536   // B*L = 16*4096
#define RPB   16      // residues per block
#define MROWS 64      // RPB*4 atom rows
#define CDIM  128
#define XSP   132     // padded float stride for xs (528 B)
#define SOP   136     // padded u16 stride for sO (272 B)

// pack two f32 -> one dword of two f16 (v_cvt_pkrtz, 1 instruction)
__device__ __forceinline__ uint32_t pkh(float a, float b) {
    f16x2 h = __builtin_amdgcn_cvt_pkrtz(a, b);
    return __builtin_bit_cast(uint32_t, h);
}

// --------------------------- W fp32 -> f16 pre-pass -------------------------
__global__ void wconv_kernel(const float* __restrict__ wq, const float* __restrict__ wk,
                             const float* __restrict__ wv, const float* __restrict__ wo,
                             uint16_t* __restrict__ dst) {
    int i = blockIdx.x * 256 + threadIdx.x;          // 65536 threads total
    const float* s = (i < 16384) ? wq : (i < 32768) ? wk : (i < 49152) ? wv : wo;
    f16 h = (f16)s[i & 16383];                       // v_cvt_f16_f32 (RNE)
    dst[i] = __builtin_bit_cast(uint16_t, h);
}

// load one 16-byte W fragment: row-major [outch][cin], 8 f16 at (row, col..col+7)
template <bool USEWS>
__device__ __forceinline__ f16x8 ldw16(const uint16_t* __restrict__ wbf,
                                       const float* __restrict__ w32,
                                       int goff, int row, int col) {
    if constexpr (USEWS) {
        return *(const f16x8*)(wbf + goff + row * CDIM + col);
    } else {
        const float4* p = (const float4*)(w32 + row * CDIM + col);
        float4 a = p[0], b = p[1];
        uint4 u = make_uint4(pkh(a.x, a.y), pkh(a.z, a.w), pkh(b.x, b.y), pkh(b.z, b.w));
        return __builtin_bit_cast(f16x8, u);
    }
}

// --------------------------------- main -------------------------------------
template <bool USEWS>
__global__ __launch_bounds__(256, 4)
void laa_main(const float* __restrict__ x, const int* __restrict__ mask,
              const float* __restrict__ Wq, const float* __restrict__ bq,
              const float* __restrict__ Wk, const float* __restrict__ bk,
              const float* __restrict__ Wv, const float* __restrict__ bv,
              const float* __restrict__ Wo, const float* __restrict__ bo,
              const uint16_t* __restrict__ wbf,
              float* __restrict__ out) {
    __shared__ float smem[MROWS * XSP];         // 33792 B, phase-reused 3x
    float*    xs = smem;                        // phase 1: fp32 x tile
    uint16_t* sO = (uint16_t*)smem;             // phase 2: f16 O tile (17408 B)
    float*    os = smem;                        // phase 3: fp32 out tile

    const int tid  = threadIdx.x;
    const int wave = tid >> 6;        // head index; owns channels [hb, hb+32)
    const int lane = tid & 63;
    const int l15  = lane & 15;
    const int quad = lane >> 4;
    const int hb   = wave * 32;
    const long m0  = (long)blockIdx.x * MROWS;

    const f32x4 vzero = {0.f, 0.f, 0.f, 0.f};

    // ---- hoisted mask loads (consumed in attention; latency fully hidden) --
    int4 mk4[4];
    #pragma unroll
    for (int m = 0; m < 4; ++m)
        mk4[m] = *(const int4*)(mask + ((long)blockIdx.x * RPB + m * 4 + quad) * 4);

    // ---- cooperative x staging: 64x128 fp32, one pass, batched issue -------
    {
        const float4* xg = (const float4*)(x + m0 * CDIM);   // 2048 chunks of 16B
        float4 xr[8];
        #pragma unroll
        for (int j = 0; j < 8; ++j) xr[j] = xg[tid + 256 * j];   // all in flight
        #pragma unroll
        for (int j = 0; j < 8; ++j) {
            int gi = tid + 256 * j;            // global chunk id
            int r = gi >> 5, c = gi & 31;      // row, 16B-chunk within row
            *(float4*)(xs + r * XSP + c * 4) = xr[j];
        }
    }
    __syncthreads();   // barrier 1: xs visible to all waves

    // ---- fused Q^T / K^T / V projection, register-resident -----------------
    // QT/KT C-layout: [outch = nd*16 + 4*quad + r, atom = l15] per row-group m
    // V    C-layout: [atom  = 4*quad + r, outch = nt*16 + l15] per row-group m
    f32x4 qt[4][2], kt[4][2], vv[4][2];
    #pragma unroll
    for (int m = 0; m < 4; ++m)
        #pragma unroll
        for (int n = 0; n < 2; ++n) { qt[m][n] = vzero; kt[m][n] = vzero; vv[m][n] = vzero; }

    #pragma unroll
    for (int ks = 0; ks < 4; ++ks) {
        // x^T-fragment from LDS: lane holds atom l15 (group m), cin ks*32+quad*8+j
        f16x8 xf[4];
        #pragma unroll
        for (int m = 0; m < 4; ++m) {
            const float* rp = xs + (m * 16 + l15) * XSP + ks * 32 + quad * 8;
            float4 a = *(const float4*)rp;
            float4 b = *(const float4*)(rp + 4);
            uint4 u = make_uint4(pkh(a.x, a.y), pkh(a.z, a.w), pkh(b.x, b.y), pkh(b.z, b.w));
            xf[m] = __builtin_bit_cast(f16x8, u);
        }
        f16x8 wqf[2], wkf[2], wvf[2];
        #pragma unroll
        for (int nt = 0; nt < 2; ++nt) {
            int row = hb + nt * 16 + l15, col = ks * 32 + quad * 8;
            wqf[nt] = ldw16<USEWS>(wbf, Wq, 0,     row, col);
            wkf[nt] = ldw16<USEWS>(wbf, Wk, 16384, row, col);
            wvf[nt] = ldw16<USEWS>(wbf, Wv, 32768, row, col);
        }
        #pragma unroll
        for (int m = 0; m < 4; ++m) {
            #pragma unroll
            for (int nt = 0; nt < 2; ++nt) {
                qt[m][nt] = __builtin_amdgcn_mfma_f32_16x16x32_f16(wqf[nt], xf[m], qt[m][nt], 0, 0, 0);
                kt[m][nt] = __builtin_amdgcn_mfma_f32_16x16x32_f16(wkf[nt], xf[m], kt[m][nt], 0, 0, 0);
                vv[m][nt] = __builtin_amdgcn_mfma_f32_16x16x32_f16(xf[m], wvf[nt], vv[m][nt], 0, 0, 0);
            }
        }
    }

    // ---- biases -------------------------------------------------------------
    const float s = 0.17677669529663689f;   // 1/sqrt(32), folded into Q side
    float bqs[8], bks[8];
    #pragma unroll
    for (int nd = 0; nd < 2; ++nd) {
        float4 q4 = *(const float4*)(bq + hb + nd * 16 + quad * 4);
        float4 k4 = *(const float4*)(bk + hb + nd * 16 + quad * 4);
        bqs[nd * 4 + 0] = q4.x * s; bqs[nd * 4 + 1] = q4.y * s;
        bqs[nd * 4 + 2] = q4.z * s; bqs[nd * 4 + 3] = q4.w * s;
        bks[nd * 4 + 0] = k4.x;     bks[nd * 4 + 1] = k4.y;
        bks[nd * 4 + 2] = k4.z;     bks[nd * 4 + 3] = k4.w;
    }
    const float bvv0 = bv[hb + l15], bvv1 = bv[hb + 16 + l15];

    __syncthreads();   // barrier 2: all xs reads done before sO overwrites smem

    // ---- attention via MFMA, softmax lane-local ----------------------------
    // scores: S^T = mfma(ktf, qtf); both frags share the implicit d-order
    // sigma(quad,j) = 4*quad + (j&3) + 16*(j>>2), so the contraction is exact.
    float rm[4];                               // residue mask for epilogue
    const bool diag = (quad == (l15 >> 2));    // lane supplies nonzero P here
    #pragma unroll
    for (int m = 0; m < 4; ++m) {
        uint4 uq, uk;
        uq.x = pkh(qt[m][0][0] * s + bqs[0], qt[m][0][1] * s + bqs[1]);
        uq.y = pkh(qt[m][0][2] * s + bqs[2], qt[m][0][3] * s + bqs[3]);
        uq.z = pkh(qt[m][1][0] * s + bqs[4], qt[m][1][1] * s + bqs[5]);
        uq.w = pkh(qt[m][1][2] * s + bqs[6], qt[m][1][3] * s + bqs[7]);
        uk.x = pkh(kt[m][0][0] + bks[0], kt[m][0][1] + bks[1]);
        uk.y = pkh(kt[m][0][2] + bks[2], kt[m][0][3] + bks[3]);
        uk.z = pkh(kt[m][1][0] + bks[4], kt[m][1][1] + bks[5]);
        uk.w = pkh(kt[m][1][2] + bks[6], kt[m][1][3] + bks[7]);
        f16x8 qtf = __builtin_bit_cast(f16x8, uq);
        f16x8 ktf = __builtin_bit_cast(f16x8, uk);
        // lane (quad,l15) -> S[q = l15, katom = 4*quad + r]
        f32x4 st = __builtin_amdgcn_mfma_f32_16x16x32_f16(ktf, qtf, vzero, 0, 0, 0);

        const int4 mk = mk4[m];
        rm[m] = (mk.x | mk.y | mk.z | mk.w) ? 1.f : 0.f;
        float mx = -3e38f;
        if (mk.x) mx = fmaxf(mx, st[0]);
        if (mk.y) mx = fmaxf(mx, st[1]);
        if (mk.z) mx = fmaxf(mx, st[2]);
        if (mk.w) mx = fmaxf(mx, st[3]);
        float e0 = mk.x ? __expf(st[0] - mx) : 0.f;
        float e1 = mk.y ? __expf(st[1] - mx) : 0.f;
        float e2 = mk.z ? __expf(st[2] - mx) : 0.f;
        float e3 = mk.w ? __expf(st[3] - mx) : 0.f;
        float inv = 1.f / (e0 + e1 + e2 + e3);   // >=1 always (max elem -> e=1)
        uint2 up = make_uint2(diag ? pkh(e0 * inv, e1 * inv) : 0u,
                              diag ? pkh(e2 * inv, e3 * inv) : 0u);
        f16x4 pf = __builtin_bit_cast(f16x4, up);  // P^T-frag: B[k=4q+j, col=q=l15]

        #pragma unroll
        for (int nt = 0; nt < 2; ++nt) {
            float bb = nt ? bvv1 : bvv0;
            uint2 uv = make_uint2(pkh(vv[m][nt][0] + bb, vv[m][nt][1] + bb),
                                  pkh(vv[m][nt][2] + bb, vv[m][nt][3] + bb));
            f16x4 vbf = __builtin_bit_cast(f16x4, uv); // A[row=d=l15, k=katom=4q+j]
            // O^T tile: lane -> [d = nt*16 + 4*quad + r, atom = l15]
            f32x4 ot = __builtin_amdgcn_mfma_f32_16x16x16f16(vbf, pf, vzero, 0, 0, 0);
            // 4 consecutive channels -> one b64 LDS write
            uint2 w2 = make_uint2(pkh(ot[0], ot[1]), pkh(ot[2], ot[3]));
            *(uint2*)(sO + (m * 16 + l15) * SOP + hb + nt * 16 + quad * 4) = w2;
        }
    }
    __syncthreads();   // barrier 3: out-proj mixes heads

    // ---- output projection: out = O @ Wo^T + bo, * residue_mask ------------
    f32x4 acc2[4][2];
    #pragma unroll
    for (int m = 0; m < 4; ++m)
        #pragma unroll
        for (int nt = 0; nt < 2; ++nt) acc2[m][nt] = vzero;

    #pragma unroll
    for (int ks = 0; ks < 4; ++ks) {
        f16x8 a2[4];
        #pragma unroll
        for (int m = 0; m < 4; ++m)   // natural A-frag: [atom=l15, c=ks*32+quad*8+j]
            a2[m] = *(const f16x8*)(sO + (m * 16 + l15) * SOP + ks * 32 + quad * 8);
        f16x8 b2[2];
        #pragma unroll
        for (int nt = 0; nt < 2; ++nt)
            b2[nt] = ldw16<USEWS>(wbf, Wo, 49152, hb + nt * 16 + l15, ks * 32 + quad * 8);
        #pragma unroll
        for (int m = 0; m < 4; ++m)
            #pragma unroll
            for (int nt = 0; nt < 2; ++nt)
                acc2[m][nt] = __builtin_amdgcn_mfma_f32_16x16x32_f16(a2[m], b2[nt], acc2[m][nt], 0, 0, 0);
    }

    __syncthreads();   // barrier 4: all sO reads done before f32 os overwrites smem

    // ---- stage final f32 tile in LDS (scatter), then coalesced nt stores ---
    {
        const float bo0 = bo[hb + l15], bo1 = bo[hb + 16 + l15];
        #pragma unroll
        for (int m = 0; m < 4; ++m) {
            // rows m*16+quad*4+r (r=0..3) all belong to local residue m*4+quad,
            // whose mask bit was cached in rm[m] by this same lane.
            #pragma unroll
            for (int nt = 0; nt < 2; ++nt) {
                float bb = nt ? bo1 : bo0;
                #pragma unroll
                for (int r = 0; r < 4; ++r)
                    os[(m * 16 + quad * 4 + r) * XSP + hb + nt * 16 + l15] =
                        (acc2[m][nt][r] + bb) * rm[m];
            }
        }
    }
    __syncthreads();   // barrier 5: os complete

    {
        f32x4* og = (f32x4*)(out + m0 * CDIM);   // 2048 chunks of 16B (ext-vector ptr)
        #pragma unroll
        for (int j = 0; j < 8; ++j) {
            int gi = tid + 256 * j;            // one contiguous 32KB block stream
            int r = gi >> 5, c = gi & 31;
            f32x4 v = *(const f32x4*)(os + r * XSP + c * 4);
            __builtin_nontemporal_store(v, og + gi);
        }
    }
}

// ------------------------------- launcher -----------------------------------
extern "C" void kernel_launch(void* const* d_in, const int* in_sizes, int n_in,
                              void* d_out, int out_size, void* d_ws, size_t ws_size,
                              hipStream_t stream) {
    const float* x    = (const float*)d_in[0];
    const int*   mask = (const int*)d_in[1];
    const float* Wq   = (const float*)d_in[2];
    const float* bq   = (const float*)d_in[3];
    const float* Wk   = (const float*)d_in[4];
    const float* bk   = (const float*)d_in[5];
    const float* Wv   = (const float*)d_in[6];
    const float* bv   = (const float*)d_in[7];
    const float* Wo   = (const float*)d_in[8];
    const float* bo   = (const float*)d_in[9];
    float* out = (float*)d_out;

    const int nblocks = N_RES / RPB;   // 4096
    const bool usews = ws_size >= (size_t)(4 * 16384 * sizeof(uint16_t));
    if (usews) {
        uint16_t* wbf = (uint16_t*)d_ws;
        wconv_kernel<<<256, 256, 0, stream>>>(Wq, Wk, Wv, Wo, wbf);
        laa_main<true><<<nblocks, 256, 0, stream>>>(x, mask, Wq, bq, Wk, bk, Wv, bv,
                                                    Wo, bo, wbf, out);
    } else {
        laa_main<false><<<nblocks, 256, 0, stream>>>(x, mask, Wq, bq, Wk, bk, Wv, bv,
                                                     Wo, bo, nullptr, out);
    }
}

// Round 7
// 339.965 us; speedup vs baseline: 1.3067x; 1.3067x over previous
//
#include <hip/hip_runtime.h>
#include <stdint.h>

// ---------------------------------------------------------------------------
// LocalAtomAttention v5 on gfx950 — register-MFMA core in v2's memory regime.
//   x:[16,4096,4,128] f32, mask:[16,4096,4] int, Wq/bq/Wk/bk/Wv/bv/Wo/bo.
// Post-mortems:
//   v2 (2.4 blk/CU, scattered stores): traffic CLEAN (67/131 MB) but latency-
//     serialized (84 VGPR, 60 back-to-back loads) -> 193 us.
//   v3/v4 (3.2-4 blk/CU): same stores, traffic EXPLODED (286-331/605-729 MB).
//     ~100 blocks/XCD x (32KB out + 32KB x) >> 4MB L2 -> partial-line dirty
//     evictions + write-allocate refetch. nt stores made it worse.
// v5 = v4 MFMA core + v2 regime:
//   - x frags per-ks from GLOBAL (no LDS staging; L2 absorbs 4-wave reuse)
//   - LDS padded to 55.3KB -> exactly 2 blocks/CU (the clean-traffic regime)
//   - __launch_bounds__(256,2): 256-VGPR cap -> loads batched, not serialized
//   - out: LDS-staged then coalesced NORMAL float4 stores (full lines, once)
//   - mask + all bias loads hoisted to kernel start (one latency window)
// ---------------------------------------------------------------------------

typedef __fp16 f16;   // storage-only; builtins want __fp16 ext-vectors
typedef f16   f16x2 __attribute__((ext_vector_type(2)));
typedef f16   f16x4 __attribute__((ext_vector_type(4)));
typedef f16   f16x8 __attribute__((ext_vector_type(8)));
typedef float f32x4 __attribute__((ext_vector_type(4)));

#define N_RES 65536   // B*L = 16*4096
#define RPB   16      // residues per block
#define MROWS 64      // RPB*4 atom rows
#define CDIM  128
#define XSP   132     // padded float stride for os (528 B)
#define SOP   136     // padded u16 stride for sO (272 B)
#define SMEMF 13824   // 55296 B declared -> floor(160K/55.3K) = 2 blocks/CU

// pack two f32 -> one dword of two f16 (v_cvt_pkrtz, 1 instruction)
__device__ __forceinline__ uint32_t pkh(float a, float b) {
    f16x2 h = __builtin_amdgcn_cvt_pkrtz(a, b);
    return __builtin_bit_cast(uint32_t, h);
}

// --------------------------- W fp32 -> f16 pre-pass -------------------------
__global__ void wconv_kernel(const float* __restrict__ wq, const float* __restrict__ wk,
                             const float* __restrict__ wv, const float* __restrict__ wo,
                             uint16_t* __restrict__ dst) {
    int i = blockIdx.x * 256 + threadIdx.x;          // 65536 threads total
    const float* s = (i < 16384) ? wq : (i < 32768) ? wk : (i < 49152) ? wv : wo;
    f16 h = (f16)s[i & 16383];                       // v_cvt_f16_f32 (RNE)
    dst[i] = __builtin_bit_cast(uint16_t, h);
}

// load one 16-byte W fragment: row-major [outch][cin], 8 f16 at (row, col..col+7)
template <bool USEWS>
__device__ __forceinline__ f16x8 ldw16(const uint16_t* __restrict__ wbf,
                                       const float* __restrict__ w32,
                                       int goff, int row, int col) {
    if constexpr (USEWS) {
        return *(const f16x8*)(wbf + goff + row * CDIM + col);
    } else {
        const float4* p = (const float4*)(w32 + row * CDIM + col);
        float4 a = p[0], b = p[1];
        uint4 u = make_uint4(pkh(a.x, a.y), pkh(a.z, a.w), pkh(b.x, b.y), pkh(b.z, b.w));
        return __builtin_bit_cast(f16x8, u);
    }
}

// --------------------------------- main -------------------------------------
template <bool USEWS>
__global__ __launch_bounds__(256, 2)
void laa_main(const float* __restrict__ x, const int* __restrict__ mask,
              const float* __restrict__ Wq, const float* __restrict__ bq,
              const float* __restrict__ Wk, const float* __restrict__ bk,
              const float* __restrict__ Wv, const float* __restrict__ bv,
              const float* __restrict__ Wo, const float* __restrict__ bo,
              const uint16_t* __restrict__ wbf,
              float* __restrict__ out) {
    __shared__ float smem[SMEMF];               // padded: occupancy governor
    uint16_t* sO = (uint16_t*)smem;             // phase A: f16 O tile (17408 B)
    float*    os = smem;                        // phase B: fp32 out tile (33792 B)

    const int tid  = threadIdx.x;
    const int wave = tid >> 6;        // head index; owns channels [hb, hb+32)
    const int lane = tid & 63;
    const int l15  = lane & 15;
    const int quad = lane >> 4;
    const int hb   = wave * 32;
    const long m0  = (long)blockIdx.x * MROWS;

    const f32x4 vzero = {0.f, 0.f, 0.f, 0.f};

    // ---- hoisted small loads: mask + all biases (one latency window) -------
    int4 mk4[4];
    #pragma unroll
    for (int m = 0; m < 4; ++m)
        mk4[m] = *(const int4*)(mask + ((long)blockIdx.x * RPB + m * 4 + quad) * 4);

    const float s = 0.17677669529663689f;   // 1/sqrt(32), folded into Q side
    float bqs[8], bks[8];
    #pragma unroll
    for (int nd = 0; nd < 2; ++nd) {
        float4 q4 = *(const float4*)(bq + hb + nd * 16 + quad * 4);
        float4 k4 = *(const float4*)(bk + hb + nd * 16 + quad * 4);
        bqs[nd * 4 + 0] = q4.x * s; bqs[nd * 4 + 1] = q4.y * s;
        bqs[nd * 4 + 2] = q4.z * s; bqs[nd * 4 + 3] = q4.w * s;
        bks[nd * 4 + 0] = k4.x;     bks[nd * 4 + 1] = k4.y;
        bks[nd * 4 + 2] = k4.z;     bks[nd * 4 + 3] = k4.w;
    }
    const float bvv0 = bv[hb + l15],      bvv1 = bv[hb + 16 + l15];
    const float bo0  = bo[hb + l15],      bo1  = bo[hb + 16 + l15];

    // ---- fused Q^T / K^T / V projection, register-resident -----------------
    // x frags straight from global per ks (v2-proven pattern, L2-served);
    // the unrolled ks loop lets the compiler pipeline loads under MFMAs.
    // QT/KT C-layout: [outch = nd*16 + 4*quad + r, atom = l15] per row-group m
    // V    C-layout: [atom  = 4*quad + r, outch = nt*16 + l15] per row-group m
    f32x4 qt[4][2], kt[4][2], vv[4][2];
    #pragma unroll
    for (int m = 0; m < 4; ++m)
        #pragma unroll
        for (int n = 0; n < 2; ++n) { qt[m][n] = vzero; kt[m][n] = vzero; vv[m][n] = vzero; }

    #pragma unroll
    for (int ks = 0; ks < 4; ++ks) {
        // x^T-fragment: lane holds atom = l15 (group m), cin = ks*32+quad*8+j
        f16x8 xf[4];
        #pragma unroll
        for (int m = 0; m < 4; ++m) {
            const float* rp = x + (m0 + m * 16 + l15) * CDIM + ks * 32 + quad * 8;
            float4 a = *(const float4*)rp;
            float4 b = *(const float4*)(rp + 4);
            uint4 u = make_uint4(pkh(a.x, a.y), pkh(a.z, a.w), pkh(b.x, b.y), pkh(b.z, b.w));
            xf[m] = __builtin_bit_cast(f16x8, u);
        }
        f16x8 wqf[2], wkf[2], wvf[2];
        #pragma unroll
        for (int nt = 0; nt < 2; ++nt) {
            int row = hb + nt * 16 + l15, col = ks * 32 + quad * 8;
            wqf[nt] = ldw16<USEWS>(wbf, Wq, 0,     row, col);
            wkf[nt] = ldw16<USEWS>(wbf, Wk, 16384, row, col);
            wvf[nt] = ldw16<USEWS>(wbf, Wv, 32768, row, col);
        }
        #pragma unroll
        for (int m = 0; m < 4; ++m) {
            #pragma unroll
            for (int nt = 0; nt < 2; ++nt) {
                qt[m][nt] = __builtin_amdgcn_mfma_f32_16x16x32_f16(wqf[nt], xf[m], qt[m][nt], 0, 0, 0);
                kt[m][nt] = __builtin_amdgcn_mfma_f32_16x16x32_f16(wkf[nt], xf[m], kt[m][nt], 0, 0, 0);
                vv[m][nt] = __builtin_amdgcn_mfma_f32_16x16x32_f16(xf[m], wvf[nt], vv[m][nt], 0, 0, 0);
            }
        }
    }

    // ---- attention via MFMA, softmax lane-local ----------------------------
    // scores: S^T = mfma(ktf, qtf); both frags share the implicit d-order
    // sigma(quad,j) = 4*quad + (j&3) + 16*(j>>2), so the contraction is exact.
    float rm[4];                               // residue mask for epilogue
    const bool diag = (quad == (l15 >> 2));    // lane supplies nonzero P here
    #pragma unroll
    for (int m = 0; m < 4; ++m) {
        uint4 uq, uk;
        uq.x = pkh(qt[m][0][0] * s + bqs[0], qt[m][0][1] * s + bqs[1]);
        uq.y = pkh(qt[m][0][2] * s + bqs[2], qt[m][0][3] * s + bqs[3]);
        uq.z = pkh(qt[m][1][0] * s + bqs[4], qt[m][1][1] * s + bqs[5]);
        uq.w = pkh(qt[m][1][2] * s + bqs[6], qt[m][1][3] * s + bqs[7]);
        uk.x = pkh(kt[m][0][0] + bks[0], kt[m][0][1] + bks[1]);
        uk.y = pkh(kt[m][0][2] + bks[2], kt[m][0][3] + bks[3]);
        uk.z = pkh(kt[m][1][0] + bks[4], kt[m][1][1] + bks[5]);
        uk.w = pkh(kt[m][1][2] + bks[6], kt[m][1][3] + bks[7]);
        f16x8 qtf = __builtin_bit_cast(f16x8, uq);
        f16x8 ktf = __builtin_bit_cast(f16x8, uk);
        // lane (quad,l15) -> S[q = l15, katom = 4*quad + r]
        f32x4 st = __builtin_amdgcn_mfma_f32_16x16x32_f16(ktf, qtf, vzero, 0, 0, 0);

        const int4 mk = mk4[m];
        rm[m] = (mk.x | mk.y | mk.z | mk.w) ? 1.f : 0.f;
        float mx = -3e38f;
        if (mk.x) mx = fmaxf(mx, st[0]);
        if (mk.y) mx = fmaxf(mx, st[1]);
        if (mk.z) mx = fmaxf(mx, st[2]);
        if (mk.w) mx = fmaxf(mx, st[3]);
        float e0 = mk.x ? __expf(st[0] - mx) : 0.f;
        float e1 = mk.y ? __expf(st[1] - mx) : 0.f;
        float e2 = mk.z ? __expf(st[2] - mx) : 0.f;
        float e3 = mk.w ? __expf(st[3] - mx) : 0.f;
        float inv = 1.f / (e0 + e1 + e2 + e3);   // >=1 always (max elem -> e=1)
        uint2 up = make_uint2(diag ? pkh(e0 * inv, e1 * inv) : 0u,
                              diag ? pkh(e2 * inv, e3 * inv) : 0u);
        f16x4 pf = __builtin_bit_cast(f16x4, up);  // P^T-frag: B[k=4q+j, col=q=l15]

        #pragma unroll
        for (int nt = 0; nt < 2; ++nt) {
            float bb = nt ? bvv1 : bvv0;
            uint2 uv = make_uint2(pkh(vv[m][nt][0] + bb, vv[m][nt][1] + bb),
                                  pkh(vv[m][nt][2] + bb, vv[m][nt][3] + bb));
            f16x4 vbf = __builtin_bit_cast(f16x4, uv); // A[row=d=l15, k=katom=4q+j]
            // O^T tile: lane -> [d = nt*16 + 4*quad + r, atom = l15]
            f32x4 ot = __builtin_amdgcn_mfma_f32_16x16x16f16(vbf, pf, vzero, 0, 0, 0);
            // 4 consecutive channels -> one b64 LDS write
            uint2 w2 = make_uint2(pkh(ot[0], ot[1]), pkh(ot[2], ot[3]));
            *(uint2*)(sO + (m * 16 + l15) * SOP + hb + nt * 16 + quad * 4) = w2;
        }
    }
    __syncthreads();   // barrier 1: out-proj mixes heads

    // ---- output projection: out = O @ Wo^T + bo, * residue_mask ------------
    f32x4 acc2[4][2];
    #pragma unroll
    for (int m = 0; m < 4; ++m)
        #pragma unroll
        for (int nt = 0; nt < 2; ++nt) acc2[m][nt] = vzero;

    #pragma unroll
    for (int ks = 0; ks < 4; ++ks) {
        f16x8 a2[4];
        #pragma unroll
        for (int m = 0; m < 4; ++m)   // natural A-frag: [atom=l15, c=ks*32+quad*8+j]
            a2[m] = *(const f16x8*)(sO + (m * 16 + l15) * SOP + ks * 32 + quad * 8);
        f16x8 b2[2];
        #pragma unroll
        for (int nt = 0; nt < 2; ++nt)
            b2[nt] = ldw16<USEWS>(wbf, Wo, 49152, hb + nt * 16 + l15, ks * 32 + quad * 8);
        #pragma unroll
        for (int m = 0; m < 4; ++m)
            #pragma unroll
            for (int nt = 0; nt < 2; ++nt)
                acc2[m][nt] = __builtin_amdgcn_mfma_f32_16x16x32_f16(a2[m], b2[nt], acc2[m][nt], 0, 0, 0);
    }

    __syncthreads();   // barrier 2: all sO reads done before os overwrites smem

    // ---- stage final f32 tile in LDS (scatter), then coalesced stores ------
    {
        #pragma unroll
        for (int m = 0; m < 4; ++m) {
            // rows m*16+quad*4+r (r=0..3) all belong to local residue m*4+quad,
            // whose mask bit was cached in rm[m] by this same lane.
            #pragma unroll
            for (int nt = 0; nt < 2; ++nt) {
                float bb = nt ? bo1 : bo0;
                #pragma unroll
                for (int r = 0; r < 4; ++r)
                    os[(m * 16 + quad * 4 + r) * XSP + hb + nt * 16 + l15] =
                        (acc2[m][nt][r] + bb) * rm[m];
            }
        }
    }
    __syncthreads();   // barrier 3: os complete

    {
        float4* og = (float4*)(out + m0 * CDIM);   // 2048 chunks of 16B
        #pragma unroll
        for (int j = 0; j < 8; ++j) {
            int gi = tid + 256 * j;            // one contiguous 32KB block stream
            int r = gi >> 5, c = gi & 31;
            *(og + gi) = *(const float4*)(os + r * XSP + c * 4);   // normal, cacheable
        }
    }
}

// ------------------------------- launcher -----------------------------------
extern "C" void kernel_launch(void* const* d_in, const int* in_sizes, int n_in,
                              void* d_out, int out_size, void* d_ws, size_t ws_size,
                              hipStream_t stream) {
    const float* x    = (const float*)d_in[0];
    const int*   mask = (const int*)d_in[1];
    const float* Wq   = (const float*)d_in[2];
    const float* bq   = (const float*)d_in[3];
    const float* Wk   = (const float*)d_in[4];
    const float* bk   = (const float*)d_in[5];
    const float* Wv   = (const float*)d_in[6];
    const float* bv   = (const float*)d_in[7];
    const float* Wo   = (const float*)d_in[8];
    const float* bo   = (const float*)d_in[9];
    float* out = (float*)d_out;

    const int nblocks = N_RES / RPB;   // 4096
    const bool usews = ws_size >= (size_t)(4 * 16384 * sizeof(uint16_t));
    if (usews) {
        uint16_t* wbf = (uint16_t*)d_ws;
        wconv_kernel<<<256, 256, 0, stream>>>(Wq, Wk, Wv, Wo, wbf);
        laa_main<true><<<nblocks, 256, 0, stream>>>(x, mask, Wq, bq, Wk, bk, Wv, bv,
                                                    Wo, bo, wbf, out);
    } else {
        laa_main<false><<<nblocks, 256, 0, stream>>>(x, mask, Wq, bq, Wk, bk, Wv, bv,
                                                     Wo, bo, nullptr, out);
    }
}

// Round 8
// 328.221 us; speedup vs baseline: 1.3534x; 1.0358x over previous
//
#include <hip/hip_runtime.h>
#include <stdint.h>

// ---------------------------------------------------------------------------
// LocalAtomAttention v6 on gfx950 — staged-x MFMA core, no-spill occupancy.
//   x:[16,4096,4,128] f32, mask:[16,4096,4] int, Wq/bq/Wk/bk/Wv/bv/Wo/bo.
// History:
//   v2/v5: clean traffic (67/131 MB) but ~57 serialized global loads/thread
//          -> 51K cyc/block, 171 us. v3/v4: x staged in LDS (right idea) but
//          __launch_bounds__(256,4) -> 128-reg cap vs ~160 needed -> SCRATCH
//          SPILL (the +220/+475 MB traffic), 255-285 us.
// v6 = v3 staging + v5 regime:
//   - x tile -> LDS once per block (8 batched coalesced float4/thread, one
//     latency window, stride 132 floats), waves read frags from LDS
//   - __launch_bounds__(256,3): 170-VGPR budget (no spill), 33.8KB LDS
//     -> 3 blocks/CU = 12 waves/CU
//   - mask + all biases hoisted; LDS-staged coalesced f32 output stores
//   - spill tripwire: expect VGPR 140-170 & WRITE ~131 MB; else revert
// ---------------------------------------------------------------------------

typedef __fp16 f16;   // storage-only; builtins want __fp16 ext-vectors
typedef f16   f16x2 __attribute__((ext_vector_type(2)));
typedef f16   f16x4 __attribute__((ext_vector_type(4)));
typedef f16   f16x8 __attribute__((ext_vector_type(8)));
typedef float f32x4 __attribute__((ext_vector_type(4)));

#define N_RES 65536   // B*L = 16*4096
#define RPB   16      // residues per block
#define MROWS 64      // RPB*4 atom rows
#define CDIM  128
#define XSP   132     // padded float stride for xs/os (528 B)
#define SOP   136     // padded u16 stride for sO (272 B)

// pack two f32 -> one dword of two f16 (v_cvt_pkrtz, 1 instruction)
__device__ __forceinline__ uint32_t pkh(float a, float b) {
    f16x2 h = __builtin_amdgcn_cvt_pkrtz(a, b);
    return __builtin_bit_cast(uint32_t, h);
}

// --------------------------- W fp32 -> f16 pre-pass -------------------------
__global__ void wconv_kernel(const float* __restrict__ wq, const float* __restrict__ wk,
                             const float* __restrict__ wv, const float* __restrict__ wo,
                             uint16_t* __restrict__ dst) {
    int i = blockIdx.x * 256 + threadIdx.x;          // 65536 threads total
    const float* s = (i < 16384) ? wq : (i < 32768) ? wk : (i < 49152) ? wv : wo;
    f16 h = (f16)s[i & 16383];                       // v_cvt_f16_f32 (RNE)
    dst[i] = __builtin_bit_cast(uint16_t, h);
}

// load one 16-byte W fragment: row-major [outch][cin], 8 f16 at (row, col..col+7)
template <bool USEWS>
__device__ __forceinline__ f16x8 ldw16(const uint16_t* __restrict__ wbf,
                                       const float* __restrict__ w32,
                                       int goff, int row, int col) {
    if constexpr (USEWS) {
        return *(const f16x8*)(wbf + goff + row * CDIM + col);
    } else {
        const float4* p = (const float4*)(w32 + row * CDIM + col);
        float4 a = p[0], b = p[1];
        uint4 u = make_uint4(pkh(a.x, a.y), pkh(a.z, a.w), pkh(b.x, b.y), pkh(b.z, b.w));
        return __builtin_bit_cast(f16x8, u);
    }
}

// --------------------------------- main -------------------------------------
template <bool USEWS>
__global__ __launch_bounds__(256, 3)
void laa_main(const float* __restrict__ x, const int* __restrict__ mask,
              const float* __restrict__ Wq, const float* __restrict__ bq,
              const float* __restrict__ Wk, const float* __restrict__ bk,
              const float* __restrict__ Wv, const float* __restrict__ bv,
              const float* __restrict__ Wo, const float* __restrict__ bo,
              const uint16_t* __restrict__ wbf,
              float* __restrict__ out) {
    __shared__ float smem[MROWS * XSP];         // 33792 B, phase-reused 3x
    float*    xs = smem;                        // phase 1: fp32 x tile
    uint16_t* sO = (uint16_t*)smem;             // phase 2: f16 O tile (17408 B)
    float*    os = smem;                        // phase 3: fp32 out tile

    const int tid  = threadIdx.x;
    const int wave = tid >> 6;        // head index; owns channels [hb, hb+32)
    const int lane = tid & 63;
    const int l15  = lane & 15;
    const int quad = lane >> 4;
    const int hb   = wave * 32;
    const long m0  = (long)blockIdx.x * MROWS;

    const f32x4 vzero = {0.f, 0.f, 0.f, 0.f};

    // ---- hoisted small loads: mask + all biases (one latency window) -------
    int4 mk4[4];
    #pragma unroll
    for (int m = 0; m < 4; ++m)
        mk4[m] = *(const int4*)(mask + ((long)blockIdx.x * RPB + m * 4 + quad) * 4);

    const float s = 0.17677669529663689f;   // 1/sqrt(32), folded into Q side
    float bqs[8], bks[8];
    #pragma unroll
    for (int nd = 0; nd < 2; ++nd) {
        float4 q4 = *(const float4*)(bq + hb + nd * 16 + quad * 4);
        float4 k4 = *(const float4*)(bk + hb + nd * 16 + quad * 4);
        bqs[nd * 4 + 0] = q4.x * s; bqs[nd * 4 + 1] = q4.y * s;
        bqs[nd * 4 + 2] = q4.z * s; bqs[nd * 4 + 3] = q4.w * s;
        bks[nd * 4 + 0] = k4.x;     bks[nd * 4 + 1] = k4.y;
        bks[nd * 4 + 2] = k4.z;     bks[nd * 4 + 3] = k4.w;
    }
    const float bvv0 = bv[hb + l15],      bvv1 = bv[hb + 16 + l15];
    const float bo0  = bo[hb + l15],      bo1  = bo[hb + 16 + l15];

    // ---- cooperative x staging: 64x128 fp32, one pass, batched issue -------
    {
        const float4* xg = (const float4*)(x + m0 * CDIM);   // 2048 chunks of 16B
        float4 xr[8];
        #pragma unroll
        for (int j = 0; j < 8; ++j) xr[j] = xg[tid + 256 * j];   // all in flight
        #pragma unroll
        for (int j = 0; j < 8; ++j) {
            int gi = tid + 256 * j;            // global chunk id
            int r = gi >> 5, c = gi & 31;      // row, 16B-chunk within row
            *(float4*)(xs + r * XSP + c * 4) = xr[j];
        }
    }
    __syncthreads();   // barrier 1: xs visible to all waves

    // ---- fused Q^T / K^T / V projection, register-resident -----------------
    // QT/KT C-layout: [outch = nd*16 + 4*quad + r, atom = l15] per row-group m
    // V    C-layout: [atom  = 4*quad + r, outch = nt*16 + l15] per row-group m
    f32x4 qt[4][2], kt[4][2], vv[4][2];
    #pragma unroll
    for (int m = 0; m < 4; ++m)
        #pragma unroll
        for (int n = 0; n < 2; ++n) { qt[m][n] = vzero; kt[m][n] = vzero; vv[m][n] = vzero; }

    #pragma unroll
    for (int ks = 0; ks < 4; ++ks) {
        // x^T-fragment from LDS: lane holds atom l15 (group m), cin ks*32+quad*8+j
        f16x8 xf[4];
        #pragma unroll
        for (int m = 0; m < 4; ++m) {
            const float* rp = xs + (m * 16 + l15) * XSP + ks * 32 + quad * 8;
            float4 a = *(const float4*)rp;
            float4 b = *(const float4*)(rp + 4);
            uint4 u = make_uint4(pkh(a.x, a.y), pkh(a.z, a.w), pkh(b.x, b.y), pkh(b.z, b.w));
            xf[m] = __builtin_bit_cast(f16x8, u);
        }
        f16x8 wqf[2], wkf[2], wvf[2];
        #pragma unroll
        for (int nt = 0; nt < 2; ++nt) {
            int row = hb + nt * 16 + l15, col = ks * 32 + quad * 8;
            wqf[nt] = ldw16<USEWS>(wbf, Wq, 0,     row, col);
            wkf[nt] = ldw16<USEWS>(wbf, Wk, 16384, row, col);
            wvf[nt] = ldw16<USEWS>(wbf, Wv, 32768, row, col);
        }
        #pragma unroll
        for (int m = 0; m < 4; ++m) {
            #pragma unroll
            for (int nt = 0; nt < 2; ++nt) {
                qt[m][nt] = __builtin_amdgcn_mfma_f32_16x16x32_f16(wqf[nt], xf[m], qt[m][nt], 0, 0, 0);
                kt[m][nt] = __builtin_amdgcn_mfma_f32_16x16x32_f16(wkf[nt], xf[m], kt[m][nt], 0, 0, 0);
                vv[m][nt] = __builtin_amdgcn_mfma_f32_16x16x32_f16(xf[m], wvf[nt], vv[m][nt], 0, 0, 0);
            }
        }
    }

    __syncthreads();   // barrier 2: all xs reads done before sO overwrites smem

    // ---- attention via MFMA, softmax lane-local ----------------------------
    // scores: S^T = mfma(ktf, qtf); both frags share the implicit d-order
    // sigma(quad,j) = 4*quad + (j&3) + 16*(j>>2), so the contraction is exact.
    float rm[4];                               // residue mask for epilogue
    const bool diag = (quad == (l15 >> 2));    // lane supplies nonzero P here
    #pragma unroll
    for (int m = 0; m < 4; ++m) {
        uint4 uq, uk;
        uq.x = pkh(qt[m][0][0] * s + bqs[0], qt[m][0][1] * s + bqs[1]);
        uq.y = pkh(qt[m][0][2] * s + bqs[2], qt[m][0][3] * s + bqs[3]);
        uq.z = pkh(qt[m][1][0] * s + bqs[4], qt[m][1][1] * s + bqs[5]);
        uq.w = pkh(qt[m][1][2] * s + bqs[6], qt[m][1][3] * s + bqs[7]);
        uk.x = pkh(kt[m][0][0] + bks[0], kt[m][0][1] + bks[1]);
        uk.y = pkh(kt[m][0][2] + bks[2], kt[m][0][3] + bks[3]);
        uk.z = pkh(kt[m][1][0] + bks[4], kt[m][1][1] + bks[5]);
        uk.w = pkh(kt[m][1][2] + bks[6], kt[m][1][3] + bks[7]);
        f16x8 qtf = __builtin_bit_cast(f16x8, uq);
        f16x8 ktf = __builtin_bit_cast(f16x8, uk);
        // lane (quad,l15) -> S[q = l15, katom = 4*quad + r]
        f32x4 st = __builtin_amdgcn_mfma_f32_16x16x32_f16(ktf, qtf, vzero, 0, 0, 0);

        const int4 mk = mk4[m];
        rm[m] = (mk.x | mk.y | mk.z | mk.w) ? 1.f : 0.f;
        float mx = -3e38f;
        if (mk.x) mx = fmaxf(mx, st[0]);
        if (mk.y) mx = fmaxf(mx, st[1]);
        if (mk.z) mx = fmaxf(mx, st[2]);
        if (mk.w) mx = fmaxf(mx, st[3]);
        float e0 = mk.x ? __expf(st[0] - mx) : 0.f;
        float e1 = mk.y ? __expf(st[1] - mx) : 0.f;
        float e2 = mk.z ? __expf(st[2] - mx) : 0.f;
        float e3 = mk.w ? __expf(st[3] - mx) : 0.f;
        float inv = 1.f / (e0 + e1 + e2 + e3);   // >=1 always (max elem -> e=1)
        uint2 up = make_uint2(diag ? pkh(e0 * inv, e1 * inv) : 0u,
                              diag ? pkh(e2 * inv, e3 * inv) : 0u);
        f16x4 pf = __builtin_bit_cast(f16x4, up);  // P^T-frag: B[k=4q+j, col=q=l15]

        #pragma unroll
        for (int nt = 0; nt < 2; ++nt) {
            float bb = nt ? bvv1 : bvv0;
            uint2 uv = make_uint2(pkh(vv[m][nt][0] + bb, vv[m][nt][1] + bb),
                                  pkh(vv[m][nt][2] + bb, vv[m][nt][3] + bb));
            f16x4 vbf = __builtin_bit_cast(f16x4, uv); // A[row=d=l15, k=katom=4q+j]
            // O^T tile: lane -> [d = nt*16 + 4*quad + r, atom = l15]
            f32x4 ot = __builtin_amdgcn_mfma_f32_16x16x16f16(vbf, pf, vzero, 0, 0, 0);
            // 4 consecutive channels -> one b64 LDS write
            uint2 w2 = make_uint2(pkh(ot[0], ot[1]), pkh(ot[2], ot[3]));
            *(uint2*)(sO + (m * 16 + l15) * SOP + hb + nt * 16 + quad * 4) = w2;
        }
    }
    __syncthreads();   // barrier 3: out-proj mixes heads

    // ---- output projection: out = O @ Wo^T + bo, * residue_mask ------------
    f32x4 acc2[4][2];
    #pragma unroll
    for (int m = 0; m < 4; ++m)
        #pragma unroll
        for (int nt = 0; nt < 2; ++nt) acc2[m][nt] = vzero;

    #pragma unroll
    for (int ks = 0; ks < 4; ++ks) {
        f16x8 a2[4];
        #pragma unroll
        for (int m = 0; m < 4; ++m)   // natural A-frag: [atom=l15, c=ks*32+quad*8+j]
            a2[m] = *(const f16x8*)(sO + (m * 16 + l15) * SOP + ks * 32 + quad * 8);
        f16x8 b2[2];
        #pragma unroll
        for (int nt = 0; nt < 2; ++nt)
            b2[nt] = ldw16<USEWS>(wbf, Wo, 49152, hb + nt * 16 + l15, ks * 32 + quad * 8);
        #pragma unroll
        for (int m = 0; m < 4; ++m)
            #pragma unroll
            for (int nt = 0; nt < 2; ++nt)
                acc2[m][nt] = __builtin_amdgcn_mfma_f32_16x16x32_f16(a2[m], b2[nt], acc2[m][nt], 0, 0, 0);
    }

    __syncthreads();   // barrier 4: all sO reads done before os overwrites smem

    // ---- stage final f32 tile in LDS (scatter), then coalesced stores ------
    {
        #pragma unroll
        for (int m = 0; m < 4; ++m) {
            // rows m*16+quad*4+r (r=0..3) all belong to local residue m*4+quad,
            // whose mask bit was cached in rm[m] by this same lane.
            #pragma unroll
            for (int nt = 0; nt < 2; ++nt) {
                float bb = nt ? bo1 : bo0;
                #pragma unroll
                for (int r = 0; r < 4; ++r)
                    os[(m * 16 + quad * 4 + r) * XSP + hb + nt * 16 + l15] =
                        (acc2[m][nt][r] + bb) * rm[m];
            }
        }
    }
    __syncthreads();   // barrier 5: os complete

    {
        float4* og = (float4*)(out + m0 * CDIM);   // 2048 chunks of 16B
        #pragma unroll
        for (int j = 0; j < 8; ++j) {
            int gi = tid + 256 * j;            // one contiguous 32KB block stream
            int r = gi >> 5, c = gi & 31;
            *(og + gi) = *(const float4*)(os + r * XSP + c * 4);   // normal, cacheable
        }
    }
}

// ------------------------------- launcher -----------------------------------
extern "C" void kernel_launch(void* const* d_in, const int* in_sizes, int n_in,
                              void* d_out, int out_size, void* d_ws, size_t ws_size,
                              hipStream_t stream) {
    const float* x    = (const float*)d_in[0];
    const int*   mask = (const int*)d_in[1];
    const float* Wq   = (const float*)d_in[2];
    const float* bq   = (const float*)d_in[3];
    const float* Wk   = (const float*)d_in[4];
    const float* bk   = (const float*)d_in[5];
    const float* Wv   = (const float*)d_in[6];
    const float* bv   = (const float*)d_in[7];
    const float* Wo   = (const float*)d_in[8];
    const float* bo   = (const float*)d_in[9];
    float* out = (float*)d_out;

    const int nblocks = N_RES / RPB;   // 4096
    const bool usews = ws_size >= (size_t)(4 * 16384 * sizeof(uint16_t));
    if (usews) {
        uint16_t* wbf = (uint16_t*)d_ws;
        wconv_kernel<<<256, 256, 0, stream>>>(Wq, Wk, Wv, Wo, wbf);
        laa_main<true><<<nblocks, 256, 0, stream>>>(x, mask, Wq, bq, Wk, bk, Wv, bv,
                                                    Wo, bo, wbf, out);
    } else {
        laa_main<false><<<nblocks, 256, 0, stream>>>(x, mask, Wq, bq, Wk, bk, Wv, bv,
                                                     Wo, bo, nullptr, out);
    }
}

// Round 9
// 279.651 us; speedup vs baseline: 1.5885x; 1.1737x over previous
//
#include <hip/hip_runtime.h>
#include <stdint.h>

// ---------------------------------------------------------------------------
// LocalAtomAttention v7 on gfx950 — batched-latency MFMA core.
//   x:[16,4096,4,128] f32, mask:[16,4096,4] int, Wq/bq/Wk/bk/Wv/bv/Wo/bo.
// v6 post-mortem: compiler allocates 84 VGPR and schedules the 32 weight
// loads/thread just-in-time -> ~12 serial latency windows -> ~24K cyc/block.
// v7 forces batching: ALL 24 QKV weight frags hoisted into named registers,
// issued before x staging (one ~40-load flight window); Wo's 8 frags issued
// at attention start (hidden under attention math). (256,2) = 256-VGPR
// budget, est. peak ~243. Everything else = v6 (staged x, MFMA attention,
// staged coalesced epilogue).
// Tripwires: VGPR_Count should jump to 230-256; WRITE ~131MB (else spill).
// ---------------------------------------------------------------------------

typedef __fp16 f16;   // storage-only; builtins want __fp16 ext-vectors
typedef f16   f16x2 __attribute__((ext_vector_type(2)));
typedef f16   f16x4 __attribute__((ext_vector_type(4)));
typedef f16   f16x8 __attribute__((ext_vector_type(8)));
typedef float f32x4 __attribute__((ext_vector_type(4)));

#define N_RES 65536   // B*L = 16*4096
#define RPB   16      // residues per block
#define MROWS 64      // RPB*4 atom rows
#define CDIM  128
#define XSP   132     // padded float stride for xs/os (528 B)
#define SOP   136     // padded u16 stride for sO (272 B)

// pack two f32 -> one dword of two f16 (v_cvt_pkrtz, 1 instruction)
__device__ __forceinline__ uint32_t pkh(float a, float b) {
    f16x2 h = __builtin_amdgcn_cvt_pkrtz(a, b);
    return __builtin_bit_cast(uint32_t, h);
}

// --------------------------- W fp32 -> f16 pre-pass -------------------------
__global__ void wconv_kernel(const float* __restrict__ wq, const float* __restrict__ wk,
                             const float* __restrict__ wv, const float* __restrict__ wo,
                             uint16_t* __restrict__ dst) {
    int i = blockIdx.x * 256 + threadIdx.x;          // 65536 threads total
    const float* s = (i < 16384) ? wq : (i < 32768) ? wk : (i < 49152) ? wv : wo;
    f16 h = (f16)s[i & 16383];                       // v_cvt_f16_f32 (RNE)
    dst[i] = __builtin_bit_cast(uint16_t, h);
}

// fallback (no workspace): pack one 16B W fragment from fp32
__device__ __forceinline__ f16x8 ldw32(const float* __restrict__ w32, int row, int col) {
    const float4* p = (const float4*)(w32 + row * CDIM + col);
    float4 a = p[0], b = p[1];
    uint4 u = make_uint4(pkh(a.x, a.y), pkh(a.z, a.w), pkh(b.x, b.y), pkh(b.z, b.w));
    return __builtin_bit_cast(f16x8, u);
}

// --------------------------------- main -------------------------------------
template <bool USEWS>
__global__ __launch_bounds__(256, 2)
void laa_main(const float* __restrict__ x, const int* __restrict__ mask,
              const float* __restrict__ Wq, const float* __restrict__ bq,
              const float* __restrict__ Wk, const float* __restrict__ bk,
              const float* __restrict__ Wv, const float* __restrict__ bv,
              const float* __restrict__ Wo, const float* __restrict__ bo,
              const uint16_t* __restrict__ wbf,
              float* __restrict__ out) {
    __shared__ float smem[MROWS * XSP];         // 33792 B, phase-reused 3x
    float*    xs = smem;                        // phase 1: fp32 x tile
    uint16_t* sO = (uint16_t*)smem;             // phase 2: f16 O tile (17408 B)
    float*    os = smem;                        // phase 3: fp32 out tile

    const int tid  = threadIdx.x;
    const int wave = tid >> 6;        // head index; owns channels [hb, hb+32)
    const int lane = tid & 63;
    const int l15  = lane & 15;
    const int quad = lane >> 4;
    const int hb   = wave * 32;
    const long m0  = (long)blockIdx.x * MROWS;

    const f32x4 vzero = {0.f, 0.f, 0.f, 0.f};

    // ---- WINDOW 1: issue ALL long-latency loads back-to-back ---------------
    // (a) 24 QKV weight fragments -> named registers (the v6 serialization fix)
    f16x8 wqr[4][2], wkr[4][2], wvr[4][2];
    if constexpr (USEWS) {
        #pragma unroll
        for (int ks = 0; ks < 4; ++ks)
            #pragma unroll
            for (int nt = 0; nt < 2; ++nt) {
                int off = (hb + nt * 16 + l15) * CDIM + ks * 32 + quad * 8;
                wqr[ks][nt] = *(const f16x8*)(wbf + off);
                wkr[ks][nt] = *(const f16x8*)(wbf + 16384 + off);
                wvr[ks][nt] = *(const f16x8*)(wbf + 32768 + off);
            }
    }
    // (b) x tile chunks (cooperative staging, consumed via LDS)
    float4 xr[8];
    {
        const float4* xg = (const float4*)(x + m0 * CDIM);   // 2048 chunks of 16B
        #pragma unroll
        for (int j = 0; j < 8; ++j) xr[j] = xg[tid + 256 * j];
    }
    // (c) mask + biases
    int4 mk4[4];
    #pragma unroll
    for (int m = 0; m < 4; ++m)
        mk4[m] = *(const int4*)(mask + ((long)blockIdx.x * RPB + m * 4 + quad) * 4);

    const float s = 0.17677669529663689f;   // 1/sqrt(32), folded into Q side
    float bqs[8], bks[8];
    #pragma unroll
    for (int nd = 0; nd < 2; ++nd) {
        float4 q4 = *(const float4*)(bq + hb + nd * 16 + quad * 4);
        float4 k4 = *(const float4*)(bk + hb + nd * 16 + quad * 4);
        bqs[nd * 4 + 0] = q4.x * s; bqs[nd * 4 + 1] = q4.y * s;
        bqs[nd * 4 + 2] = q4.z * s; bqs[nd * 4 + 3] = q4.w * s;
        bks[nd * 4 + 0] = k4.x;     bks[nd * 4 + 1] = k4.y;
        bks[nd * 4 + 2] = k4.z;     bks[nd * 4 + 3] = k4.w;
    }
    const float bvv0 = bv[hb + l15],      bvv1 = bv[hb + 16 + l15];
    const float bo0  = bo[hb + l15],      bo1  = bo[hb + 16 + l15];

    // ---- x -> LDS (waits only on xr) ---------------------------------------
    #pragma unroll
    for (int j = 0; j < 8; ++j) {
        int gi = tid + 256 * j;            // global chunk id
        int r = gi >> 5, c = gi & 31;      // row, 16B-chunk within row
        *(float4*)(xs + r * XSP + c * 4) = xr[j];
    }
    __syncthreads();   // barrier 1: xs visible to all waves

    // ---- fused Q^T / K^T / V projection, register-resident -----------------
    // QT/KT C-layout: [outch = nd*16 + 4*quad + r, atom = l15] per row-group m
    // V    C-layout: [atom  = 4*quad + r, outch = nt*16 + l15] per row-group m
    f32x4 qt[4][2], kt[4][2], vv[4][2];
    #pragma unroll
    for (int m = 0; m < 4; ++m)
        #pragma unroll
        for (int n = 0; n < 2; ++n) { qt[m][n] = vzero; kt[m][n] = vzero; vv[m][n] = vzero; }

    #pragma unroll
    for (int ks = 0; ks < 4; ++ks) {
        // x^T-fragment from LDS: lane holds atom l15 (group m), cin ks*32+quad*8+j
        f16x8 xf[4];
        #pragma unroll
        for (int m = 0; m < 4; ++m) {
            const float* rp = xs + (m * 16 + l15) * XSP + ks * 32 + quad * 8;
            float4 a = *(const float4*)rp;
            float4 b = *(const float4*)(rp + 4);
            uint4 u = make_uint4(pkh(a.x, a.y), pkh(a.z, a.w), pkh(b.x, b.y), pkh(b.z, b.w));
            xf[m] = __builtin_bit_cast(f16x8, u);
        }
        f16x8 wqf[2], wkf[2], wvf[2];
        #pragma unroll
        for (int nt = 0; nt < 2; ++nt) {
            if constexpr (USEWS) {
                wqf[nt] = wqr[ks][nt]; wkf[nt] = wkr[ks][nt]; wvf[nt] = wvr[ks][nt];
            } else {
                int row = hb + nt * 16 + l15, col = ks * 32 + quad * 8;
                wqf[nt] = ldw32(Wq, row, col);
                wkf[nt] = ldw32(Wk, row, col);
                wvf[nt] = ldw32(Wv, row, col);
            }
        }
        #pragma unroll
        for (int m = 0; m < 4; ++m) {
            #pragma unroll
            for (int nt = 0; nt < 2; ++nt) {
                qt[m][nt] = __builtin_amdgcn_mfma_f32_16x16x32_f16(wqf[nt], xf[m], qt[m][nt], 0, 0, 0);
                kt[m][nt] = __builtin_amdgcn_mfma_f32_16x16x32_f16(wkf[nt], xf[m], kt[m][nt], 0, 0, 0);
                vv[m][nt] = __builtin_amdgcn_mfma_f32_16x16x32_f16(xf[m], wvf[nt], vv[m][nt], 0, 0, 0);
            }
        }
    }

    __syncthreads();   // barrier 2: all xs reads done before sO overwrites smem

    // ---- WINDOW 2: issue Wo fragments; attention math hides their latency --
    f16x8 wor[4][2];
    if constexpr (USEWS) {
        #pragma unroll
        for (int ks = 0; ks < 4; ++ks)
            #pragma unroll
            for (int nt = 0; nt < 2; ++nt)
                wor[ks][nt] = *(const f16x8*)(wbf + 49152 +
                    (hb + nt * 16 + l15) * CDIM + ks * 32 + quad * 8);
    }

    // ---- attention via MFMA, softmax lane-local ----------------------------
    // scores: S^T = mfma(ktf, qtf); both frags share the implicit d-order
    // sigma(quad,j) = 4*quad + (j&3) + 16*(j>>2), so the contraction is exact.
    float rm[4];                               // residue mask for epilogue
    const bool diag = (quad == (l15 >> 2));    // lane supplies nonzero P here
    #pragma unroll
    for (int m = 0; m < 4; ++m) {
        uint4 uq, uk;
        uq.x = pkh(qt[m][0][0] * s + bqs[0], qt[m][0][1] * s + bqs[1]);
        uq.y = pkh(qt[m][0][2] * s + bqs[2], qt[m][0][3] * s + bqs[3]);
        uq.z = pkh(qt[m][1][0] * s + bqs[4], qt[m][1][1] * s + bqs[5]);
        uq.w = pkh(qt[m][1][2] * s + bqs[6], qt[m][1][3] * s + bqs[7]);
        uk.x = pkh(kt[m][0][0] + bks[0], kt[m][0][1] + bks[1]);
        uk.y = pkh(kt[m][0][2] + bks[2], kt[m][0][3] + bks[3]);
        uk.z = pkh(kt[m][1][0] + bks[4], kt[m][1][1] + bks[5]);
        uk.w = pkh(kt[m][1][2] + bks[6], kt[m][1][3] + bks[7]);
        f16x8 qtf = __builtin_bit_cast(f16x8, uq);
        f16x8 ktf = __builtin_bit_cast(f16x8, uk);
        // lane (quad,l15) -> S[q = l15, katom = 4*quad + r]
        f32x4 st = __builtin_amdgcn_mfma_f32_16x16x32_f16(ktf, qtf, vzero, 0, 0, 0);

        const int4 mk = mk4[m];
        rm[m] = (mk.x | mk.y | mk.z | mk.w) ? 1.f : 0.f;
        float mx = -3e38f;
        if (mk.x) mx = fmaxf(mx, st[0]);
        if (mk.y) mx = fmaxf(mx, st[1]);
        if (mk.z) mx = fmaxf(mx, st[2]);
        if (mk.w) mx = fmaxf(mx, st[3]);
        float e0 = mk.x ? __expf(st[0] - mx) : 0.f;
        float e1 = mk.y ? __expf(st[1] - mx) : 0.f;
        float e2 = mk.z ? __expf(st[2] - mx) : 0.f;
        float e3 = mk.w ? __expf(st[3] - mx) : 0.f;
        float inv = 1.f / (e0 + e1 + e2 + e3);   // >=1 always (max elem -> e=1)
        uint2 up = make_uint2(diag ? pkh(e0 * inv, e1 * inv) : 0u,
                              diag ? pkh(e2 * inv, e3 * inv) : 0u);
        f16x4 pf = __builtin_bit_cast(f16x4, up);  // P^T-frag: B[k=4q+j, col=q=l15]

        #pragma unroll
        for (int nt = 0; nt < 2; ++nt) {
            float bb = nt ? bvv1 : bvv0;
            uint2 uv = make_uint2(pkh(vv[m][nt][0] + bb, vv[m][nt][1] + bb),
                                  pkh(vv[m][nt][2] + bb, vv[m][nt][3] + bb));
            f16x4 vbf = __builtin_bit_cast(f16x4, uv); // A[row=d=l15, k=katom=4q+j]
            // O^T tile: lane -> [d = nt*16 + 4*quad + r, atom = l15]
            f32x4 ot = __builtin_amdgcn_mfma_f32_16x16x16f16(vbf, pf, vzero, 0, 0, 0);
            // 4 consecutive channels -> one b64 LDS write
            uint2 w2 = make_uint2(pkh(ot[0], ot[1]), pkh(ot[2], ot[3]));
            *(uint2*)(sO + (m * 16 + l15) * SOP + hb + nt * 16 + quad * 4) = w2;
        }
    }
    __syncthreads();   // barrier 3: out-proj mixes heads

    // ---- output projection: out = O @ Wo^T + bo, * residue_mask ------------
    f32x4 acc2[4][2];
    #pragma unroll
    for (int m = 0; m < 4; ++m)
        #pragma unroll
        for (int nt = 0; nt < 2; ++nt) acc2[m][nt] = vzero;

    #pragma unroll
    for (int ks = 0; ks < 4; ++ks) {
        f16x8 a2[4];
        #pragma unroll
        for (int m = 0; m < 4; ++m)   // natural A-frag: [atom=l15, c=ks*32+quad*8+j]
            a2[m] = *(const f16x8*)(sO + (m * 16 + l15) * SOP + ks * 32 + quad * 8);
        f16x8 b2[2];
        #pragma unroll
        for (int nt = 0; nt < 2; ++nt) {
            if constexpr (USEWS) {
                b2[nt] = wor[ks][nt];
            } else {
                b2[nt] = ldw32(Wo, hb + nt * 16 + l15, ks * 32 + quad * 8);
            }
        }
        #pragma unroll
        for (int m = 0; m < 4; ++m)
            #pragma unroll
            for (int nt = 0; nt < 2; ++nt)
                acc2[m][nt] = __builtin_amdgcn_mfma_f32_16x16x32_f16(a2[m], b2[nt], acc2[m][nt], 0, 0, 0);
    }

    __syncthreads();   // barrier 4: all sO reads done before os overwrites smem

    // ---- stage final f32 tile in LDS (scatter), then coalesced stores ------
    {
        #pragma unroll
        for (int m = 0; m < 4; ++m) {
            // rows m*16+quad*4+r (r=0..3) all belong to local residue m*4+quad,
            // whose mask bit was cached in rm[m] by this same lane.
            #pragma unroll
            for (int nt = 0; nt < 2; ++nt) {
                float bb = nt ? bo1 : bo0;
                #pragma unroll
                for (int r = 0; r < 4; ++r)
                    os[(m * 16 + quad * 4 + r) * XSP + hb + nt * 16 + l15] =
                        (acc2[m][nt][r] + bb) * rm[m];
            }
        }
    }
    __syncthreads();   // barrier 5: os complete

    {
        float4* og = (float4*)(out + m0 * CDIM);   // 2048 chunks of 16B
        #pragma unroll
        for (int j = 0; j < 8; ++j) {
            int gi = tid + 256 * j;            // one contiguous 32KB block stream
            int r = gi >> 5, c = gi & 31;
            *(og + gi) = *(const float4*)(os + r * XSP + c * 4);   // normal, cacheable
        }
    }
}

// ------------------------------- launcher -----------------------------------
extern "C" void kernel_launch(void* const* d_in, const int* in_sizes, int n_in,
                              void* d_out, int out_size, void* d_ws, size_t ws_size,
                              hipStream_t stream) {
    const float* x    = (const float*)d_in[0];
    const int*   mask = (const int*)d_in[1];
    const float* Wq   = (const float*)d_in[2];
    const float* bq   = (const float*)d_in[3];
    const float* Wk   = (const float*)d_in[4];
    const float* bk   = (const float*)d_in[5];
    const float* Wv   = (const float*)d_in[6];
    const float* bv   = (const float*)d_in[7];
    const float* Wo   = (const float*)d_in[8];
    const float* bo   = (const float*)d_in[9];
    float* out = (float*)d_out;

    const int nblocks = N_RES / RPB;   // 4096
    const bool usews = ws_size >= (size_t)(4 * 16384 * sizeof(uint16_t));
    if (usews) {
        uint16_t* wbf = (uint16_t*)d_ws;
        wconv_kernel<<<256, 256, 0, stream>>>(Wq, Wk, Wv, Wo, wbf);
        laa_main<true><<<nblocks, 256, 0, stream>>>(x, mask, Wq, bq, Wk, bk, Wv, bv,
                                                    Wo, bo, wbf, out);
    } else {
        laa_main<false><<<nblocks, 256, 0, stream>>>(x, mask, Wq, bq, Wk, bk, Wv, bv,
                                                     Wo, bo, nullptr, out);
    }
}